// Round 9
// baseline (277.718 us; speedup 1.0000x reference)
//
#include <hip/hip_runtime.h>
#include <math.h>

#define B_  4
#define T_  2048
#define H_  1024
#define NH  16
#define HD  64
#define H3  3072

typedef short bf16x8 __attribute__((ext_vector_type(8)));
typedef short bf16x4 __attribute__((ext_vector_type(4)));
typedef float f32x4  __attribute__((ext_vector_type(4)));
typedef float f32x16 __attribute__((ext_vector_type(16)));

#define SC2F 0.18033688011112042f   /* (1/sqrt(64)) * log2(e) */

__device__ __forceinline__ unsigned short f2bf(float f) {
    union { float f; unsigned u; } v; v.f = f;
    unsigned u = v.u;
    unsigned r = (u + 0x7fffu + ((u >> 16) & 1u)) >> 16;  // RNE
    return (unsigned short)r;
}

__device__ __forceinline__ void gload_lds16(const void* g, void* l) {
    __builtin_amdgcn_global_load_lds(
        (const __attribute__((address_space(1))) unsigned*)g,
        (__attribute__((address_space(3))) unsigned*)l, 16, 0, 0);
}

__device__ __forceinline__ f32x4 mfma_16x16x16_bf16(bf16x4 a, bf16x4 b, f32x4 c) {
#if __has_builtin(__builtin_amdgcn_mfma_f32_16x16x16_bf16)
    return __builtin_amdgcn_mfma_f32_16x16x16_bf16(a, b, c, 0, 0, 0);
#elif __has_builtin(__builtin_amdgcn_mfma_f32_16x16x16bf16_1k)
    return __builtin_amdgcn_mfma_f32_16x16x16bf16_1k(a, b, c, 0, 0, 0);
#else
    f32x4 d;
    asm volatile("v_mfma_f32_16x16x16_bf16 %0, %1, %2, %3"
                 : "=v"(d) : "v"(a), "v"(b), "v"(c));
    return d;
#endif
}

// ---------------------------------------------------------------------------
// Kernel 1 (fused prep): weight transpose+convert (blocks 0..4095) and
// X fp32->bf16 convert (blocks 4096..6143).
// ---------------------------------------------------------------------------
__global__ __launch_bounds__(256) void prep_kernel(
    const float* __restrict__ X, unsigned short* __restrict__ Xbf,
    const float* __restrict__ Wqkv, unsigned short* __restrict__ WqkvT,
    const float* __restrict__ Wout, unsigned short* __restrict__ WoutT)
{
    int bid = blockIdx.x;
    int t = threadIdx.x;
    if (bid < 4096) {
        __shared__ unsigned short tile[32][33];
        int bxx = bid & 127, byy = bid >> 7;
        const float* in;
        unsigned short* out;
        int N, nb;
        if (bxx < 96) { in = Wqkv; out = WqkvT; N = H3; nb = bxx * 32; }
        else          { in = Wout; out = WoutT; N = H_; nb = (bxx - 96) * 32; }
        int kb = byy * 32;
        int tx = t & 31, ty = t >> 5;
        for (int i = 0; i < 32; i += 8)
            tile[ty + i][tx] = f2bf(in[(long)(kb + ty + i) * N + nb + tx]);
        __syncthreads();
        for (int i = 0; i < 32; i += 8)
            out[(long)(nb + ty + i) * H_ + kb + tx] = tile[tx][ty + i];
    } else {
        long u = (long)(bid - 4096) * 256 + t;
#pragma unroll
        for (int j = 0; j < 4; j++) {
            long i = (u + (long)j * 524288) * 4;
            float4 v = *(const float4*)(X + i);
            ushort4 o;
            o.x = f2bf(v.x); o.y = f2bf(v.y); o.z = f2bf(v.z); o.w = f2bf(v.w);
            *(ushort4*)(Xbf + i) = o;
        }
    }
}

// ---------------------------------------------------------------------------
// Kernel 2: QKV GEMM — R6's serial 2-phase 128x128 form, NO block swizzle
// (R8 A/B: XCD swizzle REGRESSED QKV 78->85.5us, FETCH 77->84MB — per-XCD
// working set 8MB > 4MB L2 evicted B; default round-robin interleaves
// better). Best measured: 77.0-78.9us. QKV structure CLOSED: 6 variants
// tried, serial 2ph 128'/32KB wins at the documented ~27% MfmaUtil plateau.
// ---------------------------------------------------------------------------
__global__ __launch_bounds__(256) void gemm_qkv_kernel(
    const unsigned short* __restrict__ A,
    const unsigned short* __restrict__ Bt,
    const float* __restrict__ bias,
    unsigned short* __restrict__ C,
    unsigned short* __restrict__ Vt)
{
    const int K = H_, N = H3;
    __shared__ unsigned short Asm[128][64];
    __shared__ unsigned short Bsm[128][64];

    int tn = blockIdx.x * 128, tm = blockIdx.y * 128;
    int tid = threadIdx.x;
    int wid = tid >> 6, lane = tid & 63;
    int l31 = lane & 31, lh = lane >> 5;
    int wm = (wid & 1) * 64, wn = (wid >> 1) * 64;

    int rl = lane >> 3;
    int g8 = ((lane & 7) ^ rl) * 8;
    const unsigned short* aP = A  + (long)(tm + wid * 32 + rl) * K + g8;
    const unsigned short* bP = Bt + (long)(tn + wid * 32 + rl) * K + g8;
    int rk = l31 & 7;

    f32x16 acc[2][2] = {};

    for (int k0 = 0; k0 < K; k0 += 64) {
        __syncthreads();
#pragma unroll
        for (int t = 0; t < 4; t++)
            gload_lds16(aP + (long)(t * 8) * K + k0, &Asm[wid * 32 + t * 8][0]);
#pragma unroll
        for (int t = 0; t < 4; t++)
            gload_lds16(bP + (long)(t * 8) * K + k0, &Bsm[wid * 32 + t * 8][0]);
        __syncthreads();

#pragma unroll
        for (int ks = 0; ks < 4; ks++) {
            int pc = ((ks * 2 + lh) ^ rk) * 8;
            bf16x8 af[2], bv[2];
            af[0] = *(const bf16x8*)(&Asm[wm + l31][pc]);
            af[1] = *(const bf16x8*)(&Asm[wm + 32 + l31][pc]);
            bv[0] = *(const bf16x8*)(&Bsm[wn + l31][pc]);
            bv[1] = *(const bf16x8*)(&Bsm[wn + 32 + l31][pc]);
#pragma unroll
            for (int i = 0; i < 2; i++)
#pragma unroll
                for (int j = 0; j < 2; j++)
                    acc[i][j] = __builtin_amdgcn_mfma_f32_32x32x16_bf16(
                        af[i], bv[j], acc[i][j], 0, 0, 0);
        }
    }

    if (tn >= 2 * H_) {
#pragma unroll
        for (int i = 0; i < 2; i++)
#pragma unroll
            for (int j = 0; j < 2; j++) {
                int col = tn + wn + j * 32 + l31;
                float bs = bias[col];
                int feat = col - 2 * H_;
#pragma unroll
                for (int rg = 0; rg < 4; rg++) {
                    int tok0 = tm + wm + i * 32 + rg * 8 + lh * 4;
                    int bb = tok0 >> 11;
                    unsigned d0 = (unsigned)f2bf(acc[i][j][rg * 4 + 0] + bs) |
                                  ((unsigned)f2bf(acc[i][j][rg * 4 + 1] + bs) << 16);
                    unsigned d1 = (unsigned)f2bf(acc[i][j][rg * 4 + 2] + bs) |
                                  ((unsigned)f2bf(acc[i][j][rg * 4 + 3] + bs) << 16);
                    unsigned short* dst = Vt + ((long)(bb * 1024 + feat)) * T_ + (tok0 & (T_ - 1));
                    *(uint2*)dst = make_uint2(d0, d1);
                }
            }
        return;
    }

#pragma unroll
    for (int i = 0; i < 2; i++)
#pragma unroll
        for (int j = 0; j < 2; j++) {
            int col = tn + wn + j * 32 + l31;
            float bs = bias[col];
            bool ks_ = (col >= H_) && (col < 2 * H_);
#pragma unroll
            for (int r = 0; r < 16; r++) {
                int row = tm + wm + i * 32 + (r & 3) + 8 * (r >> 2) + 4 * lh;
                float v = acc[i][j][r] + bs;
                if (ks_) v *= SC2F;
                C[(long)row * N + col] = f2bf(v);
            }
        }
}

// ---------------------------------------------------------------------------
// Kernel 3: out-proj GEMM (dbuf + XCD swizzle, TN=64), unchanged.
// ---------------------------------------------------------------------------
template <int TN>
__global__ __launch_bounds__(256) void gemm_kernel(
    const unsigned short* __restrict__ A,
    const unsigned short* __restrict__ Bt,
    const float* __restrict__ bias,
    float* __restrict__ C,
    int M, int N, int K)
{
    __shared__ unsigned short Asm[2][128][64];
    __shared__ unsigned short Bsm[2][TN][64];

    int nbx = gridDim.x;
    int bid = blockIdx.y * nbx + blockIdx.x;
    int cpx = (nbx * gridDim.y) >> 3;
    int lin = (bid & 7) * cpx + (bid >> 3);
    int bx = lin % nbx, by = lin / nbx;

    int tn = bx * TN, tm = by * 128;
    int tid = threadIdx.x;
    int wid = tid >> 6, lane = tid & 63;
    int l31 = lane & 31, lh = lane >> 5;
    int wm = (wid & 1) * 64, wn = (wid >> 1) * (TN / 2);

    int rl = lane >> 3;
    int g8 = ((lane & 7) ^ rl) * 8;
    const unsigned short* aP = A  + (long)(tm + wid * 32 + rl) * K + g8;
    const unsigned short* bP = Bt + (long)(tn + wid * (TN / 4) + rl) * K + g8;
    int rk = l31 & 7;

    f32x16 acc[2][TN / 64] = {};

#pragma unroll
    for (int t = 0; t < 4; t++)
        gload_lds16(aP + (long)(t * 8) * K, &Asm[0][wid * 32 + t * 8][0]);
#pragma unroll
    for (int t = 0; t < TN / 32; t++)
        gload_lds16(bP + (long)(t * 8) * K, &Bsm[0][wid * (TN / 4) + t * 8][0]);

    int cur = 0;
    for (int k0 = 0; k0 < K; k0 += 64) {
        __syncthreads();
        if (k0 + 64 < K) {
#pragma unroll
            for (int t = 0; t < 4; t++)
                gload_lds16(aP + (long)(t * 8) * K + k0 + 64, &Asm[cur ^ 1][wid * 32 + t * 8][0]);
#pragma unroll
            for (int t = 0; t < TN / 32; t++)
                gload_lds16(bP + (long)(t * 8) * K + k0 + 64, &Bsm[cur ^ 1][wid * (TN / 4) + t * 8][0]);
        }
#pragma unroll
        for (int ks = 0; ks < 4; ks++) {
            int pc = ((ks * 2 + lh) ^ rk) * 8;
            bf16x8 af[2], bv[TN / 64];
            af[0] = *(const bf16x8*)(&Asm[cur][wm + l31][pc]);
            af[1] = *(const bf16x8*)(&Asm[cur][wm + 32 + l31][pc]);
#pragma unroll
            for (int j = 0; j < TN / 64; j++)
                bv[j] = *(const bf16x8*)(&Bsm[cur][wn + j * 32 + l31][pc]);
#pragma unroll
            for (int i = 0; i < 2; i++)
#pragma unroll
                for (int j = 0; j < TN / 64; j++)
                    acc[i][j] = __builtin_amdgcn_mfma_f32_32x32x16_bf16(
                        af[i], bv[j], acc[i][j], 0, 0, 0);
        }
        cur ^= 1;
    }

#pragma unroll
    for (int i = 0; i < 2; i++)
#pragma unroll
        for (int j = 0; j < TN / 64; j++) {
            int col = tn + wn + j * 32 + l31;
            float bs = bias[col];
#pragma unroll
            for (int r = 0; r < 16; r++) {
                int row = tm + wm + i * 32 + (r & 3) + 8 * (r >> 2) + 4 * lh;
                C[(long)row * N + col] = acc[i][j][r] + bs;
            }
        }
}

// ---------------------------------------------------------------------------
// Kernel 4: flash attention, R9 PAIR-MERGE: one block handles q-tiles
// (15-pr) [heavy] AND pr [light]. Light tile's k-range is a PREFIX of
// heavy's -> one K/V staging pass serves both (staging bytes per compute
// halved; MFMA-per-barrier doubled while kt < n_light). Combined work is
// CONSTANT (34 k-iters/block): perfect load balance. Grid 512 blocks,
// ~2 blk/CU all resident, zero tail. All per-tile state in [2]-arrays with
// statically-unrolled tt loops (rule #20). Light tile (q0<=896, len>=1024)
// is never length-masked but guards kept general.
// ---------------------------------------------------------------------------
__global__ __launch_bounds__(256) void attn_kernel(
    const unsigned short* __restrict__ QKV,
    const unsigned short* __restrict__ Vt,
    const void* __restrict__ mask,
    unsigned short* __restrict__ O)
{
    int idx = blockIdx.x;
    int bh = idx & 63;
    int pr = idx >> 6;                       // 0..7 pair index
    int b = bh >> 4, h = bh & 15;
    int q0_[2] = { (15 - pr) * 128, pr * 128 };   // [0]=heavy, [1]=light

    int tid = threadIdx.x;
    int wid = tid >> 6, lane = tid & 63, quad = lane >> 4, lr = lane & 15;
    int quad4 = quad * 4;

    // inline per-batch length (wave-redundant, L2-hot)
    int len;
    {
        const unsigned* mu = (const unsigned*)mask;
        bool is_byte = (mu[0] == 0x01010101u);
        int cnt = 0;
        if (is_byte) {
            const unsigned char* m8 = (const unsigned char*)mask;
            for (int i = lane; i < T_; i += 64) cnt += (m8[b * T_ + i] != 0);
        } else {
            const unsigned* m32 = (const unsigned*)mask;
            for (int i = lane; i < T_; i += 64) cnt += (m32[b * T_ + i] != 0);
        }
        cnt += __shfl_xor(cnt, 1);  cnt += __shfl_xor(cnt, 2);
        cnt += __shfl_xor(cnt, 4);  cnt += __shfl_xor(cnt, 8);
        cnt += __shfl_xor(cnt, 16); cnt += __shfl_xor(cnt, 32);
        len = cnt;
    }

    __shared__ __align__(16) unsigned short SH[16384];
    unsigned short (*Kd)[64][64] = (unsigned short (*)[64][64])(&SH[0]);
    unsigned short (*Vd)[64][64] = (unsigned short (*)[64][64])(&SH[8192]);

    const long qkv_base = (long)b * T_ * H3;

    // Q fragments for BOTH tiles (kt-invariant)
    bf16x8 qf[2][2][2];
#pragma unroll
    for (int tt = 0; tt < 2; tt++)
#pragma unroll
        for (int nq = 0; nq < 2; nq++)
#pragma unroll
            for (int ks = 0; ks < 2; ks++)
                qf[tt][nq][ks] = *(const bf16x8*)(QKV + qkv_base +
                    (long)(q0_[tt] + wid * 32 + nq * 16 + lr) * H3 + h * HD + ks * 32 + quad * 8);

    int rl = lane >> 3;
    int g8 = ((lane & 7) ^ rl) * 8;
    const unsigned short* kB = QKV + qkv_base + (long)(wid * 16 + rl) * H3 + H_ + h * HD + g8;
    const unsigned short* vB = Vt + (long)(bh * 64 + wid * 16 + rl) * T_ + g8;

    f32x4 lacc[2][2] = {};                  // [tile][nq]
    f32x4 Oacc[2][4][2] = {};               // [tile][md][nq]

    int qwl[2], qwh[2], nkt[2], bndv[2][2];
#pragma unroll
    for (int tt = 0; tt < 2; tt++) {
        int q_wave_lo = q0_[tt] + wid * 32;
        qwl[tt] = __builtin_amdgcn_readfirstlane(q_wave_lo);
        qwh[tt] = qwl[tt] + 31;
        bndv[tt][0] = min(q_wave_lo + lr, len - 1);
        bndv[tt][1] = min(q_wave_lo + 16 + lr, len - 1);
        int kmax = min(q0_[tt] + 127, len - 1);
        nkt[tt] = (kmax >> 6) + 1;
    }
    int n_kt = nkt[0];                      // heavy >= light always
    int rk = lr & 7;

    const short oneb = (short)0x3F80;
    bf16x4 vones = { oneb, oneb, oneb, oneb };

    // prologue: DMA tile 0 into buffer 0
#pragma unroll
    for (int t = 0; t < 2; t++) {
        gload_lds16(kB + (long)(t * 8) * H3, &Kd[0][wid * 16 + t * 8][0]);
        gload_lds16(vB + (long)(t * 8) * T_, &Vd[0][wid * 16 + t * 8][0]);
    }

    for (int kt = 0; kt < n_kt; kt++) {
        int cur = kt & 1;
        __syncthreads();   // drains DMA into buf[cur]

        if (kt + 1 < n_kt) {
            long koff = (long)((kt + 1) * 64) * H3;
            int voff = (kt + 1) * 64;
#pragma unroll
            for (int t = 0; t < 2; t++) {
                gload_lds16(kB + koff + (long)(t * 8) * H3, &Kd[cur ^ 1][wid * 16 + t * 8][0]);
                gload_lds16(vB + (long)(t * 8) * T_ + voff, &Vd[cur ^ 1][wid * 16 + t * 8][0]);
            }
        }

        int k_lo = kt * 64;

#pragma unroll
        for (int tt = 0; tt < 2; tt++) {
            if (kt >= nkt[tt]) continue;            // wave-uniform
            if (k_lo > qwh[tt] || k_lo >= len) continue;

            int mt_hi = min(qwh[tt], len - 1);
            int nmt = min(4, ((mt_hi - k_lo) >> 4) + 1);
            nmt = __builtin_amdgcn_readfirstlane(nmt);

            f32x4 Sacc[4][2] = {};
            __builtin_amdgcn_s_setprio(1);
#pragma unroll
            for (int mt = 0; mt < 4; mt++) {
                if (mt >= nmt) continue;
#pragma unroll
                for (int ks = 0; ks < 2; ks++) {
                    bf16x8 kf = *(const bf16x8*)(&Kd[cur][mt * 16 + lr][((ks * 4 + quad) ^ rk) * 8]);
                    Sacc[mt][0] = __builtin_amdgcn_mfma_f32_16x16x32_bf16(kf, qf[tt][0][ks], Sacc[mt][0], 0, 0, 0);
                    Sacc[mt][1] = __builtin_amdgcn_mfma_f32_16x16x32_bf16(kf, qf[tt][1][ks], Sacc[mt][1], 0, 0, 0);
                }
            }
            __builtin_amdgcn_s_setprio(0);

            unsigned pkk[4][2][2];
#pragma unroll
            for (int mt = 0; mt < 4; mt++) {
                if (mt >= nmt) continue;
                int kb0 = k_lo + mt * 16;
                int kbl = kb0 + quad4;
#pragma unroll
                for (int nq = 0; nq < 2; nq++) {
                    float p[4];
                    if (kb0 + 15 <= qwl[tt] + nq * 16 && kb0 + 15 < len) {
#pragma unroll
                        for (int r = 0; r < 4; r++)
                            p[r] = __builtin_amdgcn_exp2f(Sacc[mt][nq][r]);
                    } else {
                        int dlt = bndv[tt][nq] - kbl;
#pragma unroll
                        for (int r = 0; r < 4; r++) {
                            float s = (r <= dlt) ? Sacc[mt][nq][r] : -INFINITY;
                            p[r] = __builtin_amdgcn_exp2f(s);
                        }
                    }
                    pkk[mt][nq][0] = __builtin_amdgcn_perm(__float_as_uint(p[1]), __float_as_uint(p[0]), 0x07060302);
                    pkk[mt][nq][1] = __builtin_amdgcn_perm(__float_as_uint(p[3]), __float_as_uint(p[2]), 0x07060302);
                }
            }

            __builtin_amdgcn_s_setprio(1);
#pragma unroll
            for (int mt = 0; mt < 4; mt++) {
                if (mt >= nmt) continue;
                union { unsigned u[2]; bf16x4 v; } bu[2];
                bu[0].u[0] = pkk[mt][0][0]; bu[0].u[1] = pkk[mt][0][1];
                bu[1].u[0] = pkk[mt][1][0]; bu[1].u[1] = pkk[mt][1][1];
                lacc[tt][0] = mfma_16x16x16_bf16(vones, bu[0].v, lacc[tt][0]);
                lacc[tt][1] = mfma_16x16x16_bf16(vones, bu[1].v, lacc[tt][1]);
#pragma unroll
                for (int md = 0; md < 4; md++) {
                    bf16x4 vf = *(const bf16x4*)(&Vd[cur][md * 16 + lr]
                        [((mt * 2 + (quad >> 1)) ^ rk) * 8 + (quad & 1) * 4]);
                    Oacc[tt][md][0] = mfma_16x16x16_bf16(vf, bu[0].v, Oacc[tt][md][0]);
                    Oacc[tt][md][1] = mfma_16x16x16_bf16(vf, bu[1].v, Oacc[tt][md][1]);
                }
            }
            __builtin_amdgcn_s_setprio(0);
        }
    }

    // epilogue: Es scratch is wave-private (rows wid*32..+31) -> sequential
    // per-tile reuse needs only intra-wave DS ordering (lgkmcnt fences).
    __syncthreads();
    {
        unsigned short (*Es)[68] = (unsigned short (*)[68])(&SH[0]);
#pragma unroll
        for (int tt = 0; tt < 2; tt++) {
            float inv[2] = { 1.f / lacc[tt][0][0], 1.f / lacc[tt][1][0] };
#pragma unroll
            for (int nq = 0; nq < 2; nq++)
#pragma unroll
                for (int md = 0; md < 4; md++)
#pragma unroll
                    for (int rp = 0; rp < 2; rp++) {
                        float e0 = Oacc[tt][md][nq][rp * 2]     * inv[nq];
                        float e1 = Oacc[tt][md][nq][rp * 2 + 1] * inv[nq];
                        unsigned w = __builtin_amdgcn_perm(__float_as_uint(e1), __float_as_uint(e0), 0x07060302);
                        *(unsigned*)(&Es[wid * 32 + nq * 16 + lr][md * 16 + quad * 4 + rp * 2]) = w;
                    }
            __asm__ volatile("s_waitcnt lgkmcnt(0)" ::: "memory");
            __builtin_amdgcn_sched_barrier(0);
            int row = lane >> 1, cb = (lane & 1) * 32;
            long tok = (long)b * T_ + q0_[tt] + wid * 32 + row;
#pragma unroll
            for (int i = 0; i < 4; i++) {
                float4 v = *(const float4*)(&Es[wid * 32 + row][cb + i * 8]);
                *(float4*)(&O[tok * H_ + h * HD + cb + i * 8]) = v;
            }
            __asm__ volatile("s_waitcnt lgkmcnt(0)" ::: "memory");   // reads done before next tt overwrites
            __builtin_amdgcn_sched_barrier(0);
        }
    }
}

// ---------------------------------------------------------------------------
extern "C" void kernel_launch(void* const* d_in, const int* in_sizes, int n_in,
                              void* d_out, int out_size, void* d_ws, size_t ws_size,
                              hipStream_t stream) {
    const float* X    = (const float*)d_in[0];
    const void*  mask = d_in[1];
    const float* Wqkv = (const float*)d_in[2];
    const float* bqkv = (const float*)d_in[3];
    const float* Wout = (const float*)d_in[4];
    const float* bout = (const float*)d_in[5];

    char* ws = (char*)d_ws;
    unsigned short* WqkvT = (unsigned short*)(ws + 256);                // 6 MB
    unsigned short* WoutT = WqkvT + (long)H3 * H_;                      // 2 MB
    unsigned short* QKV   = WoutT + (long)H_ * H_;                      // 48 MB
    unsigned short* Xbf   = QKV + (long)B_ * T_ * H3;                   // 16 MB
    unsigned short* Vt    = Xbf + (long)B_ * T_ * H_;                   // 16 MB
    unsigned short* Obf   = Xbf;  // O reuses X region (X dead after QKV GEMM)

    const int M = B_ * T_;  // 8192

    prep_kernel<<<6144, 256, 0, stream>>>(X, Xbf, Wqkv, WqkvT, Wout, WoutT);
    gemm_qkv_kernel<<<dim3(H3 / 128, M / 128), 256, 0, stream>>>(
        Xbf, WqkvT, bqkv, QKV, Vt);
    attn_kernel<<<B_ * NH * 8, 256, 0, stream>>>(QKV, Vt, mask, Obf);
    gemm_kernel<64><<<dim3(H_ / 64, M / 128), 256, 0, stream>>>(
        Obf, WoutT, bout, (float*)d_out, M, H_, H_);
}

// Round 10
// 262.152 us; speedup vs baseline: 1.0594x; 1.0594x over previous
//
#include <hip/hip_runtime.h>
#include <math.h>

#define B_  4
#define T_  2048
#define H_  1024
#define NH  16
#define HD  64
#define H3  3072

typedef short bf16x8 __attribute__((ext_vector_type(8)));
typedef short bf16x4 __attribute__((ext_vector_type(4)));
typedef float f32x4  __attribute__((ext_vector_type(4)));
typedef float f32x16 __attribute__((ext_vector_type(16)));

#define SC2F 0.18033688011112042f   /* (1/sqrt(64)) * log2(e) */

__device__ __forceinline__ unsigned short f2bf(float f) {
    union { float f; unsigned u; } v; v.f = f;
    unsigned u = v.u;
    unsigned r = (u + 0x7fffu + ((u >> 16) & 1u)) >> 16;  // RNE
    return (unsigned short)r;
}

__device__ __forceinline__ void gload_lds16(const void* g, void* l) {
    __builtin_amdgcn_global_load_lds(
        (const __attribute__((address_space(1))) unsigned*)g,
        (__attribute__((address_space(3))) unsigned*)l, 16, 0, 0);
}

__device__ __forceinline__ f32x4 mfma_16x16x16_bf16(bf16x4 a, bf16x4 b, f32x4 c) {
#if __has_builtin(__builtin_amdgcn_mfma_f32_16x16x16_bf16)
    return __builtin_amdgcn_mfma_f32_16x16x16_bf16(a, b, c, 0, 0, 0);
#elif __has_builtin(__builtin_amdgcn_mfma_f32_16x16x16bf16_1k)
    return __builtin_amdgcn_mfma_f32_16x16x16bf16_1k(a, b, c, 0, 0, 0);
#else
    f32x4 d;
    asm volatile("v_mfma_f32_16x16x16_bf16 %0, %1, %2, %3"
                 : "=v"(d) : "v"(a), "v"(b), "v"(c));
    return d;
#endif
}

// ---------------------------------------------------------------------------
// Kernel 1 (fused prep): weight transpose+convert (blocks 0..4095) and
// X fp32->bf16 convert (blocks 4096..6143). prep is at HBM roofline
// (~75 MB moved ~= 12.5us).
// ---------------------------------------------------------------------------
__global__ __launch_bounds__(256) void prep_kernel(
    const float* __restrict__ X, unsigned short* __restrict__ Xbf,
    const float* __restrict__ Wqkv, unsigned short* __restrict__ WqkvT,
    const float* __restrict__ Wout, unsigned short* __restrict__ WoutT)
{
    int bid = blockIdx.x;
    int t = threadIdx.x;
    if (bid < 4096) {
        __shared__ unsigned short tile[32][33];
        int bxx = bid & 127, byy = bid >> 7;
        const float* in;
        unsigned short* out;
        int N, nb;
        if (bxx < 96) { in = Wqkv; out = WqkvT; N = H3; nb = bxx * 32; }
        else          { in = Wout; out = WoutT; N = H_; nb = (bxx - 96) * 32; }
        int kb = byy * 32;
        int tx = t & 31, ty = t >> 5;
        for (int i = 0; i < 32; i += 8)
            tile[ty + i][tx] = f2bf(in[(long)(kb + ty + i) * N + nb + tx]);
        __syncthreads();
        for (int i = 0; i < 32; i += 8)
            out[(long)(nb + ty + i) * H_ + kb + tx] = tile[tx][ty + i];
    } else {
        long u = (long)(bid - 4096) * 256 + t;
#pragma unroll
        for (int j = 0; j < 4; j++) {
            long i = (u + (long)j * 524288) * 4;
            float4 v = *(const float4*)(X + i);
            ushort4 o;
            o.x = f2bf(v.x); o.y = f2bf(v.y); o.z = f2bf(v.z); o.w = f2bf(v.w);
            *(ushort4*)(Xbf + i) = o;
        }
    }
}

// ---------------------------------------------------------------------------
// Kernel 2: QKV GEMM — serial 2-phase 128x128, BK=64, 32KB LDS, no swizzle.
// BEST MEASURED of 7 variants (77.0-78.9us): dbuf 84.1, 8ph 87.4, 4ph 86.4,
// 256'-serial 87.0, +XCD-swizzle 85.5 (L2 working-set thrash). The 2-phase
// structure lives off inter-block overlap; 128'/32KB (4-5 blk/CU) is its
// local optimum at the documented ~27% MfmaUtil K=1024 plateau. CLOSED.
// ---------------------------------------------------------------------------
__global__ __launch_bounds__(256) void gemm_qkv_kernel(
    const unsigned short* __restrict__ A,
    const unsigned short* __restrict__ Bt,
    const float* __restrict__ bias,
    unsigned short* __restrict__ C,
    unsigned short* __restrict__ Vt)
{
    const int K = H_, N = H3;
    __shared__ unsigned short Asm[128][64];
    __shared__ unsigned short Bsm[128][64];

    int tn = blockIdx.x * 128, tm = blockIdx.y * 128;
    int tid = threadIdx.x;
    int wid = tid >> 6, lane = tid & 63;
    int l31 = lane & 31, lh = lane >> 5;
    int wm = (wid & 1) * 64, wn = (wid >> 1) * 64;

    int rl = lane >> 3;
    int g8 = ((lane & 7) ^ rl) * 8;
    const unsigned short* aP = A  + (long)(tm + wid * 32 + rl) * K + g8;
    const unsigned short* bP = Bt + (long)(tn + wid * 32 + rl) * K + g8;
    int rk = l31 & 7;

    f32x16 acc[2][2] = {};

    for (int k0 = 0; k0 < K; k0 += 64) {
        __syncthreads();
#pragma unroll
        for (int t = 0; t < 4; t++)
            gload_lds16(aP + (long)(t * 8) * K + k0, &Asm[wid * 32 + t * 8][0]);
#pragma unroll
        for (int t = 0; t < 4; t++)
            gload_lds16(bP + (long)(t * 8) * K + k0, &Bsm[wid * 32 + t * 8][0]);
        __syncthreads();

#pragma unroll
        for (int ks = 0; ks < 4; ks++) {
            int pc = ((ks * 2 + lh) ^ rk) * 8;
            bf16x8 af[2], bv[2];
            af[0] = *(const bf16x8*)(&Asm[wm + l31][pc]);
            af[1] = *(const bf16x8*)(&Asm[wm + 32 + l31][pc]);
            bv[0] = *(const bf16x8*)(&Bsm[wn + l31][pc]);
            bv[1] = *(const bf16x8*)(&Bsm[wn + 32 + l31][pc]);
#pragma unroll
            for (int i = 0; i < 2; i++)
#pragma unroll
                for (int j = 0; j < 2; j++)
                    acc[i][j] = __builtin_amdgcn_mfma_f32_32x32x16_bf16(
                        af[i], bv[j], acc[i][j], 0, 0, 0);
        }
    }

    if (tn >= 2 * H_) {
#pragma unroll
        for (int i = 0; i < 2; i++)
#pragma unroll
            for (int j = 0; j < 2; j++) {
                int col = tn + wn + j * 32 + l31;
                float bs = bias[col];
                int feat = col - 2 * H_;
#pragma unroll
                for (int rg = 0; rg < 4; rg++) {
                    int tok0 = tm + wm + i * 32 + rg * 8 + lh * 4;
                    int bb = tok0 >> 11;
                    unsigned d0 = (unsigned)f2bf(acc[i][j][rg * 4 + 0] + bs) |
                                  ((unsigned)f2bf(acc[i][j][rg * 4 + 1] + bs) << 16);
                    unsigned d1 = (unsigned)f2bf(acc[i][j][rg * 4 + 2] + bs) |
                                  ((unsigned)f2bf(acc[i][j][rg * 4 + 3] + bs) << 16);
                    unsigned short* dst = Vt + ((long)(bb * 1024 + feat)) * T_ + (tok0 & (T_ - 1));
                    *(uint2*)dst = make_uint2(d0, d1);
                }
            }
        return;
    }

#pragma unroll
    for (int i = 0; i < 2; i++)
#pragma unroll
        for (int j = 0; j < 2; j++) {
            int col = tn + wn + j * 32 + l31;
            float bs = bias[col];
            bool ks_ = (col >= H_) && (col < 2 * H_);
#pragma unroll
            for (int r = 0; r < 16; r++) {
                int row = tm + wm + i * 32 + (r & 3) + 8 * (r >> 2) + 4 * lh;
                float v = acc[i][j][r] + bs;
                if (ks_) v *= SC2F;
                C[(long)row * N + col] = f2bf(v);
            }
        }
}

// ---------------------------------------------------------------------------
// Kernel 3: out-proj GEMM (dbuf + XCD swizzle, TN=64 — R2's measured win).
// ---------------------------------------------------------------------------
template <int TN>
__global__ __launch_bounds__(256) void gemm_kernel(
    const unsigned short* __restrict__ A,
    const unsigned short* __restrict__ Bt,
    const float* __restrict__ bias,
    float* __restrict__ C,
    int M, int N, int K)
{
    __shared__ unsigned short Asm[2][128][64];
    __shared__ unsigned short Bsm[2][TN][64];

    int nbx = gridDim.x;
    int bid = blockIdx.y * nbx + blockIdx.x;
    int cpx = (nbx * gridDim.y) >> 3;
    int lin = (bid & 7) * cpx + (bid >> 3);
    int bx = lin % nbx, by = lin / nbx;

    int tn = bx * TN, tm = by * 128;
    int tid = threadIdx.x;
    int wid = tid >> 6, lane = tid & 63;
    int l31 = lane & 31, lh = lane >> 5;
    int wm = (wid & 1) * 64, wn = (wid >> 1) * (TN / 2);

    int rl = lane >> 3;
    int g8 = ((lane & 7) ^ rl) * 8;
    const unsigned short* aP = A  + (long)(tm + wid * 32 + rl) * K + g8;
    const unsigned short* bP = Bt + (long)(tn + wid * (TN / 4) + rl) * K + g8;
    int rk = l31 & 7;

    f32x16 acc[2][TN / 64] = {};

#pragma unroll
    for (int t = 0; t < 4; t++)
        gload_lds16(aP + (long)(t * 8) * K, &Asm[0][wid * 32 + t * 8][0]);
#pragma unroll
    for (int t = 0; t < TN / 32; t++)
        gload_lds16(bP + (long)(t * 8) * K, &Bsm[0][wid * (TN / 4) + t * 8][0]);

    int cur = 0;
    for (int k0 = 0; k0 < K; k0 += 64) {
        __syncthreads();
        if (k0 + 64 < K) {
#pragma unroll
            for (int t = 0; t < 4; t++)
                gload_lds16(aP + (long)(t * 8) * K + k0 + 64, &Asm[cur ^ 1][wid * 32 + t * 8][0]);
#pragma unroll
            for (int t = 0; t < TN / 32; t++)
                gload_lds16(bP + (long)(t * 8) * K + k0 + 64, &Bsm[cur ^ 1][wid * (TN / 4) + t * 8][0]);
        }
#pragma unroll
        for (int ks = 0; ks < 4; ks++) {
            int pc = ((ks * 2 + lh) ^ rk) * 8;
            bf16x8 af[2], bv[TN / 64];
            af[0] = *(const bf16x8*)(&Asm[cur][wm + l31][pc]);
            af[1] = *(const bf16x8*)(&Asm[cur][wm + 32 + l31][pc]);
#pragma unroll
            for (int j = 0; j < TN / 64; j++)
                bv[j] = *(const bf16x8*)(&Bsm[cur][wn + j * 32 + l31][pc]);
#pragma unroll
            for (int i = 0; i < 2; i++)
#pragma unroll
                for (int j = 0; j < TN / 64; j++)
                    acc[i][j] = __builtin_amdgcn_mfma_f32_32x32x16_bf16(
                        af[i], bv[j], acc[i][j], 0, 0, 0);
        }
        cur ^= 1;
    }

#pragma unroll
    for (int i = 0; i < 2; i++)
#pragma unroll
        for (int j = 0; j < TN / 64; j++) {
            int col = tn + wn + j * 32 + l31;
            float bs = bias[col];
#pragma unroll
            for (int r = 0; r < 16; r++) {
                int row = tm + wm + i * 32 + (r & 3) + 8 * (r >> 2) + 4 * lh;
                C[(long)row * N + col] = acc[i][j][r] + bs;
            }
        }
}

// ---------------------------------------------------------------------------
// Kernel 4: flash attention — R6-passing single-tile form, RESTORED.
// (R9 pair-merge A/B: 73 -> 87us despite FETCH 30->23MB — halving block
// count halves waves/CU; this kernel lives off inter-block MFMA||VALU
// overlap, same lesson as the GEMM dbuf/256' nulls. 1024 blocks heavy-first
// self-schedules the imbalance.) Inline per-batch length; ones-MFMA
// denominator; wave-uniform nmt skip; single-compare mask; setprio.
// ---------------------------------------------------------------------------
__global__ __launch_bounds__(256) void attn_kernel(
    const unsigned short* __restrict__ QKV,
    const unsigned short* __restrict__ Vt,
    const void* __restrict__ mask,
    unsigned short* __restrict__ O)
{
    int idx = blockIdx.x;
    int bh = idx & 63;
    int qt = 15 - (idx >> 6);
    int b = bh >> 4, h = bh & 15;
    int q0 = qt * 128;

    int tid = threadIdx.x;
    int wid = tid >> 6, lane = tid & 63, quad = lane >> 4, lr = lane & 15;
    int quad4 = quad * 4;

    int len;
    {
        const unsigned* mu = (const unsigned*)mask;
        bool is_byte = (mu[0] == 0x01010101u);
        int cnt = 0;
        if (is_byte) {
            const unsigned char* m8 = (const unsigned char*)mask;
            for (int i = lane; i < T_; i += 64) cnt += (m8[b * T_ + i] != 0);
        } else {
            const unsigned* m32 = (const unsigned*)mask;
            for (int i = lane; i < T_; i += 64) cnt += (m32[b * T_ + i] != 0);
        }
        cnt += __shfl_xor(cnt, 1);  cnt += __shfl_xor(cnt, 2);
        cnt += __shfl_xor(cnt, 4);  cnt += __shfl_xor(cnt, 8);
        cnt += __shfl_xor(cnt, 16); cnt += __shfl_xor(cnt, 32);
        len = cnt;
    }

    __shared__ __align__(16) unsigned short SH[16384];
    unsigned short (*Kd)[64][64] = (unsigned short (*)[64][64])(&SH[0]);
    unsigned short (*Vd)[64][64] = (unsigned short (*)[64][64])(&SH[8192]);

    const long qkv_base = (long)b * T_ * H3;

    bf16x8 qf[2][2];
#pragma unroll
    for (int nq = 0; nq < 2; nq++)
#pragma unroll
        for (int ks = 0; ks < 2; ks++)
            qf[nq][ks] = *(const bf16x8*)(QKV + qkv_base +
                (long)(q0 + wid * 32 + nq * 16 + lr) * H3 + h * HD + ks * 32 + quad * 8);

    int rl = lane >> 3;
    int g8 = ((lane & 7) ^ rl) * 8;
    const unsigned short* kB = QKV + qkv_base + (long)(wid * 16 + rl) * H3 + H_ + h * HD + g8;
    const unsigned short* vB = Vt + (long)(bh * 64 + wid * 16 + rl) * T_ + g8;

    f32x4 lacc[2] = {};
    f32x4 Oacc[4][2] = {};

    int kmax = min(q0 + 127, len - 1);
    int n_kt = (kmax >> 6) + 1;
    int q_wave_lo = q0 + wid * 32;
    int qwl_u = __builtin_amdgcn_readfirstlane(q_wave_lo);
    int q_wave_hi = qwl_u + 31;
    int bnd_[2] = { min(q_wave_lo + lr, len - 1),
                    min(q_wave_lo + 16 + lr, len - 1) };
    int rk = lr & 7;

    const short oneb = (short)0x3F80;
    bf16x4 vones = { oneb, oneb, oneb, oneb };

#pragma unroll
    for (int t = 0; t < 2; t++) {
        gload_lds16(kB + (long)(t * 8) * H3, &Kd[0][wid * 16 + t * 8][0]);
        gload_lds16(vB + (long)(t * 8) * T_, &Vd[0][wid * 16 + t * 8][0]);
    }

    for (int kt = 0; kt < n_kt; kt++) {
        int cur = kt & 1;
        __syncthreads();

        if (kt + 1 < n_kt) {
            long koff = (long)((kt + 1) * 64) * H3;
            int voff = (kt + 1) * 64;
#pragma unroll
            for (int t = 0; t < 2; t++) {
                gload_lds16(kB + koff + (long)(t * 8) * H3, &Kd[cur ^ 1][wid * 16 + t * 8][0]);
                gload_lds16(vB + (long)(t * 8) * T_ + voff, &Vd[cur ^ 1][wid * 16 + t * 8][0]);
            }
        }

        int k_lo = kt * 64;
        if (k_lo > q_wave_hi || k_lo >= len) continue;

        int mt_hi = min(q_wave_hi, len - 1);
        int nmt = min(4, ((mt_hi - k_lo) >> 4) + 1);
        nmt = __builtin_amdgcn_readfirstlane(nmt);

        f32x4 Sacc[4][2] = {};
        __builtin_amdgcn_s_setprio(1);
#pragma unroll
        for (int mt = 0; mt < 4; mt++) {
            if (mt >= nmt) continue;
#pragma unroll
            for (int ks = 0; ks < 2; ks++) {
                bf16x8 kf = *(const bf16x8*)(&Kd[cur][mt * 16 + lr][((ks * 4 + quad) ^ rk) * 8]);
                Sacc[mt][0] = __builtin_amdgcn_mfma_f32_16x16x32_bf16(kf, qf[0][ks], Sacc[mt][0], 0, 0, 0);
                Sacc[mt][1] = __builtin_amdgcn_mfma_f32_16x16x32_bf16(kf, qf[1][ks], Sacc[mt][1], 0, 0, 0);
            }
        }
        __builtin_amdgcn_s_setprio(0);

        unsigned pkk[4][2][2];
#pragma unroll
        for (int mt = 0; mt < 4; mt++) {
            if (mt >= nmt) continue;
            int kb0 = k_lo + mt * 16;
            int kbl = kb0 + quad4;
#pragma unroll
            for (int nq = 0; nq < 2; nq++) {
                float p[4];
                if (kb0 + 15 <= qwl_u + nq * 16 && kb0 + 15 < len) {
#pragma unroll
                    for (int r = 0; r < 4; r++)
                        p[r] = __builtin_amdgcn_exp2f(Sacc[mt][nq][r]);
                } else {
                    int dlt = bnd_[nq] - kbl;
#pragma unroll
                    for (int r = 0; r < 4; r++) {
                        float s = (r <= dlt) ? Sacc[mt][nq][r] : -INFINITY;
                        p[r] = __builtin_amdgcn_exp2f(s);
                    }
                }
                pkk[mt][nq][0] = __builtin_amdgcn_perm(__float_as_uint(p[1]), __float_as_uint(p[0]), 0x07060302);
                pkk[mt][nq][1] = __builtin_amdgcn_perm(__float_as_uint(p[3]), __float_as_uint(p[2]), 0x07060302);
            }
        }

        __builtin_amdgcn_s_setprio(1);
#pragma unroll
        for (int mt = 0; mt < 4; mt++) {
            if (mt >= nmt) continue;
            union { unsigned u[2]; bf16x4 v; } bu[2];
            bu[0].u[0] = pkk[mt][0][0]; bu[0].u[1] = pkk[mt][0][1];
            bu[1].u[0] = pkk[mt][1][0]; bu[1].u[1] = pkk[mt][1][1];
            lacc[0] = mfma_16x16x16_bf16(vones, bu[0].v, lacc[0]);
            lacc[1] = mfma_16x16x16_bf16(vones, bu[1].v, lacc[1]);
#pragma unroll
            for (int md = 0; md < 4; md++) {
                bf16x4 vf = *(const bf16x4*)(&Vd[cur][md * 16 + lr]
                    [((mt * 2 + (quad >> 1)) ^ rk) * 8 + (quad & 1) * 4]);
                Oacc[md][0] = mfma_16x16x16_bf16(vf, bu[0].v, Oacc[md][0]);
                Oacc[md][1] = mfma_16x16x16_bf16(vf, bu[1].v, Oacc[md][1]);
            }
        }
        __builtin_amdgcn_s_setprio(0);
    }

    __syncthreads();
    {
        unsigned short (*Es)[68] = (unsigned short (*)[68])(&SH[0]);
        float inv[2] = { 1.f / lacc[0][0], 1.f / lacc[1][0] };
#pragma unroll
        for (int nq = 0; nq < 2; nq++)
#pragma unroll
            for (int md = 0; md < 4; md++)
#pragma unroll
                for (int rp = 0; rp < 2; rp++) {
                    float e0 = Oacc[md][nq][rp * 2]     * inv[nq];
                    float e1 = Oacc[md][nq][rp * 2 + 1] * inv[nq];
                    unsigned w = __builtin_amdgcn_perm(__float_as_uint(e1), __float_as_uint(e0), 0x07060302);
                    *(unsigned*)(&Es[wid * 32 + nq * 16 + lr][md * 16 + quad * 4 + rp * 2]) = w;
                }
        __asm__ volatile("s_waitcnt lgkmcnt(0)" ::: "memory");
        int row = lane >> 1, cb = (lane & 1) * 32;
        long tok = (long)b * T_ + q0 + wid * 32 + row;
#pragma unroll
        for (int i = 0; i < 4; i++) {
            float4 v = *(const float4*)(&Es[wid * 32 + row][cb + i * 8]);
            *(float4*)(&O[tok * H_ + h * HD + cb + i * 8]) = v;
        }
    }
}

// ---------------------------------------------------------------------------
extern "C" void kernel_launch(void* const* d_in, const int* in_sizes, int n_in,
                              void* d_out, int out_size, void* d_ws, size_t ws_size,
                              hipStream_t stream) {
    const float* X    = (const float*)d_in[0];
    const void*  mask = d_in[1];
    const float* Wqkv = (const float*)d_in[2];
    const float* bqkv = (const float*)d_in[3];
    const float* Wout = (const float*)d_in[4];
    const float* bout = (const float*)d_in[5];

    char* ws = (char*)d_ws;
    unsigned short* WqkvT = (unsigned short*)(ws + 256);                // 6 MB
    unsigned short* WoutT = WqkvT + (long)H3 * H_;                      // 2 MB
    unsigned short* QKV   = WoutT + (long)H_ * H_;                      // 48 MB
    unsigned short* Xbf   = QKV + (long)B_ * T_ * H3;                   // 16 MB
    unsigned short* Vt    = Xbf + (long)B_ * T_ * H_;                   // 16 MB
    unsigned short* Obf   = Xbf;  // O reuses X region (X dead after QKV GEMM)

    const int M = B_ * T_;  // 8192

    prep_kernel<<<6144, 256, 0, stream>>>(X, Xbf, Wqkv, WqkvT, Wout, WoutT);
    gemm_qkv_kernel<<<dim3(H3 / 128, M / 128), 256, 0, stream>>>(
        Xbf, WqkvT, bqkv, QKV, Vt);
    attn_kernel<<<B_ * NH * (T_ / 128), 256, 0, stream>>>(QKV, Vt, mask, Obf);
    gemm_kernel<64><<<dim3(H_ / 64, M / 128), 256, 0, stream>>>(
        Obf, WoutT, bout, (float*)d_out, M, H_, H_);
}